// Round 10
// baseline (1042.518 us; speedup 1.0000x reference)
//
#include <hip/hip_runtime.h>
#include <math.h>

#define BB 4096
#define CC 50257
#define C4 (CC / 4)          // 12564 float4 chunks + 1 scalar tail (col 50256)
#define RAT_AVG_F 0.02f
#define IMAX 0x7fffffff

// Output layout (floats): [0]=bootstrap, [1..4096]=s, [4097..8192]=zmax',
// [8193..12288]=max9d', [12289..16384]=max8d', [16385]=sum(1-s), [16386..20481]=s*max_9
#define OFF_S     1
#define OFF_ZMAX  (1 + BB)
#define OFF_M9D   (1 + 2*BB)
#define OFF_M8D   (1 + 3*BB)
#define OFF_CNT   (1 + 4*BB)
#define OFF_MAX9  (2 + 4*BB)

// Branch-free top-3 (value,index) insert. With the invariant v0>=v1>=v2 the
// value updates are clamps (median-of-3 degenerates):
//   nv1 = min(v0, max(v1, x)); nv2 = min(OLD v1, max(v2, x)); v0 = max(v0, x)
// -> 5 value min/max + 3 v_cmp + 5 index cndmask = 13 VALU ops/element,
// all on independent compare chains (good ILP). Strict '>' keeps the earliest
// (lowest index) on value ties -- valid because each per-thread stream sees
// strictly increasing indices.
__device__ __forceinline__ void ins3(float x, int j,
                                     float& v0, int& i0,
                                     float& v1, int& i1,
                                     float& v2, int& i2) {
    bool b0 = x > v0, b1 = x > v1, b2 = x > v2;
    float nv2 = fminf(v1, fmaxf(v2, x));   // uses OLD v1
    float nv1 = fminf(v0, fmaxf(v1, x));
    int   ni1 = b0 ? i0 : (b1 ? j : i1);
    int   ni2 = b1 ? i1 : (b2 ? j : i2);
    v0 = fmaxf(v0, x);
    i0 = b0 ? j : i0;
    v1 = nv1; i1 = ni1;
    v2 = nv2; i2 = ni2;
}

// Compound-compare merge (value desc, index asc) for cross-stream / cross-lane
// / cross-wave merges where index order is not monotone. Branch-free. Rare path.
__device__ __forceinline__ void merge1(float xv, int jj,
                                       float& v0, int& i0,
                                       float& v1, int& i1,
                                       float& v2, int& i2) {
    bool b0 = (xv > v0) || (xv == v0 && jj < i0);
    bool b1 = (xv > v1) || (xv == v1 && jj < i1);
    bool b2 = (xv > v2) || (xv == v2 && jj < i2);
    float nv1 = b0 ? v0 : (b1 ? xv : v1);
    int   ni1 = b0 ? i0 : (b1 ? jj : i1);
    float nv2 = b1 ? v1 : (b2 ? xv : v2);
    int   ni2 = b1 ? i1 : (b2 ? jj : i2);
    v0 = b0 ? xv : v0; i0 = b0 ? jj : i0;
    v1 = nv1; i1 = ni1;
    v2 = nv2; i2 = ni2;
}

__global__ __launch_bounds__(256) void row_stats_kernel(const float* __restrict__ y_pred,
                                                        const int* __restrict__ y,
                                                        float* __restrict__ out,
                                                        float* __restrict__ boot_ws) {
    const int row = blockIdx.x;
    const int tid = threadIdx.x;
    const float* rp = y_pred + (size_t)row * CC;
    const float4* rp4 = (const float4*)rp;

    // label gather issued early; its HBM latency hides under the scan
    float xy = 0.0f;
    if (tid == 0) { int lbl = y[row]; xy = rp[lbl]; }

    // Two independent (value,index) top-3 streams to break the per-element
    // dependent chain and double memory-level parallelism.
    float a0 = -INFINITY, a1 = -INFINITY, a2 = -INFINITY;
    int   ai0 = IMAX, ai1 = IMAX, ai2 = IMAX;
    float c0 = -INFINITY, c1 = -INFINITY, c2 = -INFINITY;
    int   ci0 = IMAX, ci1 = IMAX, ci2 = IMAX;
    float sumA = 0.0f, sumB = 0.0f;

    int i = tid;
    for (; i + 256 < C4; i += 512) {
        float4 xa = rp4[i];
        float4 xb = rp4[i + 256];
        int ja = i << 2;
        int jb = ja + 1024;            // (i+256)<<2
        sumA += (__expf(xa.x) + __expf(xa.y)) + (__expf(xa.z) + __expf(xa.w));
        sumB += (__expf(xb.x) + __expf(xb.y)) + (__expf(xb.z) + __expf(xb.w));
        ins3(xa.x, ja,     a0, ai0, a1, ai1, a2, ai2);
        ins3(xa.y, ja + 1, a0, ai0, a1, ai1, a2, ai2);
        ins3(xa.z, ja + 2, a0, ai0, a1, ai1, a2, ai2);
        ins3(xa.w, ja + 3, a0, ai0, a1, ai1, a2, ai2);
        ins3(xb.x, jb,     c0, ci0, c1, ci1, c2, ci2);
        ins3(xb.y, jb + 1, c0, ci0, c1, ci1, c2, ci2);
        ins3(xb.z, jb + 2, c0, ci0, c1, ci1, c2, ci2);
        ins3(xb.w, jb + 3, c0, ci0, c1, ci1, c2, ci2);
    }
    for (; i < C4; i += 256) {     // at most one leftover chunk per thread
        float4 xa = rp4[i];
        int ja = i << 2;
        sumA += (__expf(xa.x) + __expf(xa.y)) + (__expf(xa.z) + __expf(xa.w));
        ins3(xa.x, ja,     a0, ai0, a1, ai1, a2, ai2);
        ins3(xa.y, ja + 1, a0, ai0, a1, ai1, a2, ai2);
        ins3(xa.z, ja + 2, a0, ai0, a1, ai1, a2, ai2);
        ins3(xa.w, ja + 3, a0, ai0, a1, ai1, a2, ai2);
    }
    if (tid == 0) {  // scalar tail element (col 50256)
        float x = rp[CC - 1];
        sumA += __expf(x);
        ins3(x, CC - 1, a0, ai0, a1, ai1, a2, ai2);
    }

    // merge stream B into A (indices interleave -> compound compare)
    merge1(c0, ci0, a0, ai0, a1, ai1, a2, ai2);
    merge1(c1, ci1, a0, ai0, a1, ai1, a2, ai2);
    merge1(c2, ci2, a0, ai0, a1, ai1, a2, ai2);
    float sum = sumA + sumB;

    // wave (64-lane) reduction; only lane 0's result is consumed
    #pragma unroll
    for (int off = 32; off; off >>= 1) {
        float ov0 = __shfl_down(a0, off), ov1 = __shfl_down(a1, off), ov2 = __shfl_down(a2, off);
        int   oi0 = __shfl_down(ai0, off), oi1 = __shfl_down(ai1, off), oi2 = __shfl_down(ai2, off);
        sum += __shfl_down(sum, off);
        merge1(ov0, oi0, a0, ai0, a1, ai1, a2, ai2);
        merge1(ov1, oi1, a0, ai0, a1, ai1, a2, ai2);
        merge1(ov2, oi2, a0, ai0, a1, ai1, a2, ai2);
    }

    __shared__ float sv0[4], sv1[4], sv2[4], ssum[4];
    __shared__ int   si0[4], si1[4], si2[4];
    if ((tid & 63) == 0) {
        int w = tid >> 6;
        sv0[w] = a0; sv1[w] = a1; sv2[w] = a2; ssum[w] = sum;
        si0[w] = ai0; si1[w] = ai1; si2[w] = ai2;
    }
    __syncthreads();

    if (tid == 0) {
        #pragma unroll
        for (int w = 1; w < 4; ++w) {
            sum += ssum[w];
            merge1(sv0[w], si0[w], a0, ai0, a1, ai1, a2, ai2);
            merge1(sv1[w], si1[w], a0, ai0, a1, ai1, a2, ai2);
            merge1(sv2[w], si2[w], a0, ai0, a1, ai1, a2, ai2);
        }
        float S    = sum;
        float logS = __logf(S);
        float fy   = __expf(xy) / S;
        bool  sflg = fy < RAT_AVG_F;

        float e0 = __expf(a0), e1 = __expf(a1), e2 = __expf(a2);
        float boot;
        if (sflg) {
            float inv_w = 1.0f / (e0 + e1 + e2);
            boot = -(e0 * (a0 - logS) + e1 * (a1 - logS) + e2 * (a2 - logS)) * inv_w;
        } else {
            boot = -(xy - logS);
        }
        boot_ws[row]        = boot;
        out[OFF_S + row]    = sflg ? 1.0f : 0.0f;
        out[OFF_ZMAX + row] = sflg ? (float)ai0 : -1.0f;
        out[OFF_M9D + row]  = sflg ? (float)ai1 : -1.0f;
        out[OFF_M8D + row]  = sflg ? (float)ai2 : -1.0f;
        out[OFF_MAX9 + row] = sflg ? (e1 / S) : 0.0f;
    }
}

__global__ __launch_bounds__(256) void final_reduce_kernel(const float* __restrict__ boot_ws,
                                                           float* __restrict__ out) {
    const int tid = threadIdx.x;
    float bsum = 0.0f, csum = 0.0f;
    for (int i = tid; i < BB; i += 256) {
        bsum += boot_ws[i];
        csum += 1.0f - out[OFF_S + i];
    }
    #pragma unroll
    for (int off = 32; off; off >>= 1) {
        bsum += __shfl_down(bsum, off);
        csum += __shfl_down(csum, off);
    }
    __shared__ float sb[4], sc[4];
    if ((tid & 63) == 0) { sb[tid >> 6] = bsum; sc[tid >> 6] = csum; }
    __syncthreads();
    if (tid == 0) {
        float b = 0.0f, c = 0.0f;
        #pragma unroll
        for (int w = 0; w < 4; ++w) { b += sb[w]; c += sc[w]; }
        out[0]       = b / (float)BB;
        out[OFF_CNT] = c;
    }
}

extern "C" void kernel_launch(void* const* d_in, const int* in_sizes, int n_in,
                              void* d_out, int out_size, void* d_ws, size_t ws_size,
                              hipStream_t stream) {
    const float* y_pred = (const float*)d_in[0];
    const int*   y      = (const int*)d_in[1];
    float* out     = (float*)d_out;
    float* boot_ws = (float*)d_ws;  // BB floats

    row_stats_kernel<<<BB, 256, 0, stream>>>(y_pred, y, out, boot_ws);
    final_reduce_kernel<<<1, 256, 0, stream>>>(boot_ws, out);
}